// Round 5
// baseline (116.449 us; speedup 1.0000x reference)
//
#include <hip/hip_runtime.h>
#include <hip/hip_bf16.h>

// ---------------------------------------------------------------------------
// LossNet: x (12288,128) fp32 -> scalar loss.  bsz=4096.
// 5 full matrices (zx/zy folded into colsums of xz/yz):
//   task 0 xx, 1 yy, 2 xy, 3 xz (+colsum->s_zx), 4 yz (+colsum->s_zy)
// All reductions are exclusive non-atomic stores (R3: atomics serialized).
// R5: 5120 fine blocks (2 tiles each) for occupancy; zero-C MFMA init;
// single-store colsum LDS.  R4 was stall-bound: 17% occ, both pipes idle.
// ---------------------------------------------------------------------------

typedef __attribute__((ext_vector_type(8))) short short8;   // 8 x bf16
typedef __attribute__((ext_vector_type(4))) float floatx4;  // MFMA acc

#define D      128
#define BM     128    // rows per block
#define BN     64     // cols per j-tile
#define BPAD   136    // LDS row stride in shorts (2-way alias = free)
#define JSPLIT 32     // column splits; 2 j-tiles per block
#define NTPB   2
// grid: 5 tasks x 32 iblk x 32 jsplit
#define GRID_EXPSIM (5 * 32 * 32)

// ---------------------------------------------------------------------------
// Kernel 1: row-normalize fp32 -> bf16, prescaled by sqrt(10*log2(e)) so the
// MFMA dot product is already the exp2 argument.  Also zeroes out[0].
// ---------------------------------------------------------------------------
__global__ __launch_bounds__(256) void normalize_kernel(
    const float* __restrict__ x, short* __restrict__ xn,
    float* __restrict__ out, int rows) {
  int tid = threadIdx.x;
  if (blockIdx.x == 0 && tid == 0) out[0] = 0.0f;

  int row  = blockIdx.x * 4 + (tid >> 6);
  int lane = tid & 63;
  if (row >= rows) return;
  const float2* xr = (const float2*)(x + (size_t)row * D);
  float2 v = xr[lane];
  float s = v.x * v.x + v.y * v.y;
#pragma unroll
  for (int off = 1; off < 64; off <<= 1) s += __shfl_xor(s, off, 64);
  // sqrt(10 / ln 2): dot(a,b) = 10*log2(e)*cos -> e^(10 cos) = exp2(dot)
  float scale = 3.7982825470322528f / fmaxf(sqrtf(s), 1e-12f);
  __hip_bfloat162 h;
  h.x = __float2bfloat16(v.x * scale);
  h.y = __float2bfloat16(v.y * scale);
  ((__hip_bfloat162*)xn)[(size_t)row * 64 + lane] = h;
}

// ---------------------------------------------------------------------------
// Epilogue: exp2, rowsum partials (registers), optional colsum -> LDS slot
// (written exactly once, no zeroing), optional diag store.
// C/D layout: col=lm, row=quad*4+reg  [m89-verified]
// ---------------------------------------------------------------------------
template <bool COL, bool DIAG>
__device__ __forceinline__ void epilogue(
    const floatx4 (&acc)[2][4], float (&rs)[2][4], int rowg0, int colg0,
    int quad, int lm, int w, int t, float* __restrict__ csLDS,
    float* __restrict__ diag_ptr) {
  float cs[4] = {0.f, 0.f, 0.f, 0.f};
#pragma unroll
  for (int mi = 0; mi < 2; mi++) {
#pragma unroll
    for (int r = 0; r < 4; r++) {
      int rowg = rowg0 + mi * 16 + quad * 4 + r;
      float part = 0.f;
#pragma unroll
      for (int ni = 0; ni < 4; ni++) {
        float e = exp2f(acc[mi][ni][r]);   // acc = 10*log2(e)*cos
        part += e;
        if (COL) cs[ni] += e;
        if (DIAG) {
          if (colg0 + ni * 16 + lm == rowg) diag_ptr[rowg] = e;
        }
      }
      rs[mi][r] += part;
    }
  }
  if (COL) {
    // reduce across quads (rows within wave); each (w,t,ni,lm) slot is
    // written exactly once per block -> plain store
#pragma unroll
    for (int ni = 0; ni < 4; ni++) {
      float v = cs[ni];
      v += __shfl_xor(v, 16, 64);
      v += __shfl_xor(v, 32, 64);
      if (quad == 0) csLDS[w * 128 + t * 64 + ni * 16 + lm] = v;
    }
  }
}

// ---------------------------------------------------------------------------
// Kernel 2: exp-sim.  block = (task, iblk, jsplit); 2 j-tiles of 128x64.
// NOTE: plain __launch_bounds__(256) — min-waves cap spills acc/frags (R2).
// ---------------------------------------------------------------------------
__global__ __launch_bounds__(256) void expsim_kernel(
    const short* __restrict__ xn,
    float* __restrict__ srow,   // [5][JSPLIT][4096] exclusive
    float* __restrict__ scol,   // [2][32][4096] exclusive
    float* __restrict__ diag,   // [5][4096] exclusive
    int bsz) {
  __shared__ short ldsB[BN * BPAD];
  __shared__ float csLDS[4 * 128];   // [wave][tile*64 + col]

  int tid = threadIdx.x;
  int bx  = blockIdx.x;
  int task   = bx >> 10;     // 1024 blocks per task
  int rem    = bx & 1023;
  int iblk   = rem >> 5;
  int jsplit = rem & 31;

  const int aoff_t[5] = {0, 1, 0, 0, 1};
  const int boff_t[5] = {0, 1, 1, 2, 2};
  int arow0     = aoff_t[task] * bsz + iblk * BM;
  int brow_base = boff_t[task] * bsz;
  bool col_en   = (task >= 3);
  bool dg       = (jsplit == iblk);   // both tiles lie on the diagonal band

  int w    = tid >> 6;     // wave: rows w*32..w*32+31
  int lane = tid & 63;
  int quad = lane >> 4;
  int lm   = lane & 15;
  int rowg0 = iblk * BM + w * 32;

  float* diag_ptr = diag + task * bsz;

  // ---- A fragments, resident for whole block ----
  short8 afrag[2][4];
#pragma unroll
  for (int mi = 0; mi < 2; mi++) {
    int r = arow0 + w * 32 + mi * 16 + lm;
    const short8* ap = (const short8*)(xn + (size_t)r * D);
#pragma unroll
    for (int kk = 0; kk < 4; kk++) afrag[mi][kk] = ap[kk * 4 + quad];
  }

  float rs[2][4];
#pragma unroll
  for (int mi = 0; mi < 2; mi++)
#pragma unroll
    for (int r = 0; r < 4; r++) rs[mi][r] = 0.0f;

  const floatx4 z4 = {0.f, 0.f, 0.f, 0.f};   // hoisted zero C-operand

  // ---- 2 j-tiles per block ----
  for (int t = 0; t < NTPB; t++) {
    int jt    = jsplit * NTPB + t;
    int colg0 = jt * BN;
    __syncthreads();
    const short* bsrc = xn + ((size_t)brow_base + colg0) * D;
#pragma unroll
    for (int it = 0; it < 4; it++) {
      int c = it * 256 + tid;
      int br = c >> 4, c16 = c & 15;
      *(short8*)(&ldsB[br * BPAD + c16 * 8]) =
          *(const short8*)(bsrc + (size_t)br * D + c16 * 8);
    }
    __syncthreads();

    floatx4 acc[2][4];
#pragma unroll
    for (int kk = 0; kk < 4; kk++) {
      short8 bfrag[4];
#pragma unroll
      for (int ni = 0; ni < 4; ni++)
        bfrag[ni] = *(const short8*)(&ldsB[(ni * 16 + lm) * BPAD + kk * 32 + quad * 8]);
#pragma unroll
      for (int mi = 0; mi < 2; mi++)
#pragma unroll
        for (int ni = 0; ni < 4; ni++)
          acc[mi][ni] = __builtin_amdgcn_mfma_f32_16x16x32_bf16(
              afrag[mi][kk], bfrag[ni], (kk == 0) ? z4 : acc[mi][ni], 0, 0, 0);
    }

    if (col_en) {
      if (dg) epilogue<true, true>(acc, rs, rowg0, colg0, quad, lm, w, t, csLDS, diag_ptr);
      else    epilogue<true, false>(acc, rs, rowg0, colg0, quad, lm, w, t, csLDS, diag_ptr);
    } else {
      if (dg) epilogue<false, true>(acc, rs, rowg0, colg0, quad, lm, w, t, csLDS, diag_ptr);
      else    epilogue<false, false>(acc, rs, rowg0, colg0, quad, lm, w, t, csLDS, diag_ptr);
    }
  }

  // ---- row-sum flush: reduce over lm within quad, exclusive store ----
  float* srow_ptr = srow + ((size_t)(task * JSPLIT + jsplit)) * bsz;
#pragma unroll
  for (int mi = 0; mi < 2; mi++) {
#pragma unroll
    for (int r = 0; r < 4; r++) {
      float v = rs[mi][r];
      v += __shfl_xor(v, 1, 64);
      v += __shfl_xor(v, 2, 64);
      v += __shfl_xor(v, 4, 64);
      v += __shfl_xor(v, 8, 64);
      if (lm == 0) srow_ptr[rowg0 + mi * 16 + quad * 4 + r] = v;
    }
  }

  // ---- col-sum flush: cross-wave LDS reduce, exclusive store ----
  if (col_en) {
    __syncthreads();
    float* scol_ptr = scol + ((size_t)((task - 3) * 32 + iblk)) * bsz + jsplit * 128;
    if (tid < 128)
      scol_ptr[tid] = csLDS[tid] + csLDS[128 + tid] + csLDS[256 + tid] + csLDS[384 + tid];
  }
}

// ---------------------------------------------------------------------------
// Kernel 3: final loss reduction.  16 blocks x 256 threads, one row each.
// ---------------------------------------------------------------------------
__global__ __launch_bounds__(256) void reduce_kernel(
    const float* __restrict__ srow, const float* __restrict__ scol,
    const float* __restrict__ diag, float* __restrict__ out, int bsz) {
  int tid = threadIdx.x;
  int i   = blockIdx.x * 256 + tid;

  float s[5];
#pragma unroll
  for (int t = 0; t < 5; t++) {
    float a = 0.f;
#pragma unroll 8
    for (int js = 0; js < JSPLIT; js++) a += srow[(size_t)(t * JSPLIT + js) * bsz + i];
    s[t] = a;
  }
  float s_zx = 0.f, s_zy = 0.f;
#pragma unroll 8
  for (int ib = 0; ib < 32; ib++) {
    s_zx += scol[(size_t)ib * bsz + i];
    s_zy += scol[(size_t)(32 + ib) * bsz + i];
  }
  float d_xx = diag[0 * bsz + i], d_yy = diag[1 * bsz + i];
  float d_xy = diag[2 * bsz + i], d_ax = diag[3 * bsz + i];
  float d_ay = diag[4 * bsz + i];

  float denom = (s[2] - d_xy) + (s[0] - d_xx) + (s[1] - d_yy);
  float tloc = -2.0f * __logf(d_xy / denom);
  tloc -= __logf(d_ax / (s[3] - d_ax));
  tloc -= __logf(d_ay / (s[4] - d_ay));
  tloc -= __logf(d_ax / (s_zx - d_ax));   // d_zx == d_ax
  tloc -= __logf(d_ay / (s_zy - d_ay));   // d_zy == d_ay

  __shared__ float red[256];
  red[tid] = tloc;
  __syncthreads();
  for (int st = 128; st > 0; st >>= 1) {
    if (tid < st) red[tid] += red[tid + st];
    __syncthreads();
  }
  if (tid == 0) atomicAdd(out, red[0] / (float)bsz);
}

// ---------------------------------------------------------------------------
extern "C" void kernel_launch(void* const* d_in, const int* in_sizes, int n_in,
                              void* d_out, int out_size, void* d_ws, size_t ws_size,
                              hipStream_t stream) {
  const float* x = (const float*)d_in[0];
  int rows = in_sizes[0] / D;   // 12288
  int bsz  = rows / 3;          // 4096

  char*  ws       = (char*)d_ws;
  short* xn       = (short*)ws;                        // rows*D bf16: 3 MiB
  size_t xn_bytes = (size_t)rows * D * sizeof(short);
  float* srow     = (float*)(ws + xn_bytes);           // [5][32][4096]: 2.5 MiB
  float* scol     = srow + 5 * JSPLIT * bsz;           // [2][32][4096]: 1 MiB
  float* diag     = scol + 2 * 32 * bsz;               // [5][4096]: 80 KiB

  normalize_kernel<<<rows / 4, 256, 0, stream>>>(x, xn, (float*)d_out, rows);
  expsim_kernel<<<GRID_EXPSIM, 256, 0, stream>>>(xn, srow, scol, diag, bsz);
  reduce_kernel<<<bsz / 256, 256, 0, stream>>>(srow, scol, diag, (float*)d_out, bsz);
}

// Round 6
// 100.644 us; speedup vs baseline: 1.1570x; 1.1570x over previous
//
#include <hip/hip_runtime.h>
#include <hip/hip_bf16.h>

// ---------------------------------------------------------------------------
// LossNet: x (12288,128) fp32 -> scalar loss.  bsz=4096.
// 5 matrices (zx/zy folded into colsums of xz/yz):
//   task 0 xx, 1 yy, 2 xy, 3 xz (+colsum->s_zx), 4 yz (+colsum->s_zy)
// R6: barrier-free expsim.  normalize emits a fragment-native layout
//   xnf[group g=row/16][kk=k/32][lane][8]  (lane = quad*16+lm; element =
//   row g*16+lm, k = kk*32+quad*8+j), so every MFMA A/B fragment is ONE
//   coalesced global_load_dwordx4.  No LDS staging, no per-tile barriers.
// exp = __builtin_amdgcn_exp2f (raw v_exp_f32); inputs prescaled so the
// MFMA dot product is already the exp2 argument.  (R4/R5 post-mortem:
// exp2f() is ocml-precise, multi-inst — it RAISED VALU cost vs __expf.)
// All reductions exclusive non-atomic stores (R3: atomics serialized).
// ---------------------------------------------------------------------------

typedef __attribute__((ext_vector_type(8))) short short8;   // 8 x bf16
typedef __attribute__((ext_vector_type(4))) float floatx4;  // MFMA acc

#define D   128
#define BSZ 4096
#define GPM 256          // 16-row groups per matrix (4096/16)
// expsim grid: 5 tasks x 32 iblk(128 rows) x 8 jsp(512 cols)
#define GRID_EXPSIM (5 * 32 * 8)

// ---------------------------------------------------------------------------
// Kernel 1: row-normalize fp32 -> bf16 into fragment-native layout,
// prescaled by sqrt(10*log2(e)).  One wave per row.  Also zeroes out[0].
// ---------------------------------------------------------------------------
__global__ __launch_bounds__(256) void normalize_kernel(
    const float* __restrict__ x, __hip_bfloat162* __restrict__ xnf2,
    float* __restrict__ out, int rows) {
  int tid = threadIdx.x;
  if (blockIdx.x == 0 && tid == 0) out[0] = 0.0f;

  int row  = blockIdx.x * 4 + (tid >> 6);
  int lane = tid & 63;
  if (row >= rows) return;
  const float2* xr = (const float2*)(x + (size_t)row * D);
  float2 v = xr[lane];
  float s = v.x * v.x + v.y * v.y;
#pragma unroll
  for (int off = 1; off < 64; off <<= 1) s += __shfl_xor(s, off, 64);
  // sqrt(10 / ln 2): dot(a,b) = 10*log2(e)*cos -> e^(10 cos) = exp2(dot)
  float scale = 3.7982825470322528f / fmaxf(sqrtf(s), 1e-12f);
  __hip_bfloat162 h;
  h.x = __float2bfloat16(v.x * scale);
  h.y = __float2bfloat16(v.y * scale);
  // fragment-native scatter: k0 = lane*2
  // short idx = g*2048 + kk*512 + (quad*16 + (row&15))*8 + j   (as bf162: /2)
  int g    = row >> 4;
  int kk   = lane >> 4;            // k0>>5
  int quad = (lane >> 2) & 3;      // (k0>>3)&3
  int jj   = lane & 3;             // (k0&7)/2
  xnf2[g * 1024 + kk * 256 + (quad * 16 + (row & 15)) * 4 + jj] = h;
}

// ---------------------------------------------------------------------------
// Epilogue: exp2 (1 inst), rowsum partials (regs), optional colsum partials,
// optional diag store.  C/D layout: col=lm, row=quad*4+reg  [m89-verified]
// ---------------------------------------------------------------------------
template <bool COL, bool DIAG>
__device__ __forceinline__ void epilogue(
    const floatx4 (&acc)[2][4], float (&rs)[2][4], float (&cs)[4],
    int rowg0, int colg0, int quad, int lm, float* __restrict__ diag_ptr) {
#pragma unroll
  for (int mi = 0; mi < 2; mi++) {
#pragma unroll
    for (int r = 0; r < 4; r++) {
      int rowg = rowg0 + mi * 16 + quad * 4 + r;
      float part = 0.f;
#pragma unroll
      for (int ni = 0; ni < 4; ni++) {
        float e = __builtin_amdgcn_exp2f(acc[mi][ni][r]);  // v_exp_f32
        part += e;
        if (COL) cs[ni] += e;
        if (DIAG) {
          if (colg0 + ni * 16 + lm == rowg) diag_ptr[rowg] = e;
        }
      }
      rs[mi][r] += part;
    }
  }
}

// ---------------------------------------------------------------------------
// Kernel 2: exp-sim, barrier-free K-loop.  block = (task, ib, jsp);
// wave w covers rows ib*128+w*32 .. +32, cols jsp*512 .. +512 (8 tiles of 64).
// NOTE: plain __launch_bounds__(256) — min-waves cap spills (R2).
// ---------------------------------------------------------------------------
__global__ __launch_bounds__(256) void expsim_kernel(
    const short8* __restrict__ xnf8,
    float* __restrict__ srow,   // [5][8][4096] exclusive
    float* __restrict__ scol,   // [2][32][4096] exclusive
    float* __restrict__ diag) { // [5][4096] exclusive
  __shared__ float csLDS[4 * 512];   // colsum accum, tasks 3-4 only

  int tid = threadIdx.x;
  int bx  = blockIdx.x;
  int task = bx >> 8;          // 256 blocks per task
  int rem  = bx & 255;
  int ib   = rem >> 3;         // 32 row-blocks of 128
  int jsp  = rem & 7;          // 8 col-groups of 512

  const int aoff_t[5] = {0, 1, 0, 0, 1};
  const int boff_t[5] = {0, 1, 1, 2, 2};
  bool col_en = (task >= 3);

  int w    = tid >> 6;
  int lane = tid & 63;
  int quad = lane >> 4;
  int lm   = lane & 15;
  int rowg0 = ib * 128 + w * 32;

  // diagonal-owning tile: jt_d = ib*2 + (w>>1); block-uniform jsp match
  bool dgblk = (jsp == (ib >> 2));
  int  tdiag = ((ib & 3) * 2) + (w >> 1);   // local tile index if dgblk

  float* diag_ptr = diag + task * BSZ;

  // ---- A fragments (one coalesced b128 each), resident whole wave ----
  int gA = aoff_t[task] * GPM + ib * 8 + w * 2;
  short8 afrag[2][4];
#pragma unroll
  for (int mi = 0; mi < 2; mi++)
#pragma unroll
    for (int kk = 0; kk < 4; kk++)
      afrag[mi][kk] = xnf8[(size_t)(gA + mi) * 256 + kk * 64 + lane];

  float rs[2][4];
#pragma unroll
  for (int mi = 0; mi < 2; mi++)
#pragma unroll
    for (int r = 0; r < 4; r++) rs[mi][r] = 0.0f;

  const floatx4 z4 = {0.f, 0.f, 0.f, 0.f};
  int gB0 = boff_t[task] * GPM + jsp * 32;   // 8 tiles x 4 groups

  // ---- 8 j-tiles, no barriers: loads/MFMA/epilogue free-run ----
#pragma unroll
  for (int t = 0; t < 8; t++) {
    int colg0 = (jsp * 8 + t) * 64;
    floatx4 acc[2][4];
#pragma unroll
    for (int kk = 0; kk < 4; kk++) {
      short8 bf[4];
#pragma unroll
      for (int ni = 0; ni < 4; ni++)
        bf[ni] = xnf8[(size_t)(gB0 + t * 4 + ni) * 256 + kk * 64 + lane];
#pragma unroll
      for (int mi = 0; mi < 2; mi++)
#pragma unroll
        for (int ni = 0; ni < 4; ni++)
          acc[mi][ni] = __builtin_amdgcn_mfma_f32_16x16x32_bf16(
              afrag[mi][kk], bf[ni], (kk == 0) ? z4 : acc[mi][ni], 0, 0, 0);
    }

    float cs[4] = {0.f, 0.f, 0.f, 0.f};
    bool dg = dgblk && (t == tdiag);   // wave-uniform
    if (col_en) {
      if (dg) epilogue<true, true>(acc, rs, cs, rowg0, colg0, quad, lm, diag_ptr);
      else    epilogue<true, false>(acc, rs, cs, rowg0, colg0, quad, lm, diag_ptr);
      // reduce across quads (rows within wave); each slot written once
#pragma unroll
      for (int ni = 0; ni < 4; ni++) {
        float v = cs[ni];
        v += __shfl_xor(v, 16, 64);
        v += __shfl_xor(v, 32, 64);
        if (quad == 0) csLDS[w * 512 + t * 64 + ni * 16 + lm] = v;
      }
    } else {
      if (dg) epilogue<false, true>(acc, rs, cs, rowg0, colg0, quad, lm, diag_ptr);
      else    epilogue<false, false>(acc, rs, cs, rowg0, colg0, quad, lm, diag_ptr);
    }
  }

  // ---- row-sum flush: reduce over lm within quad, exclusive store ----
  float* srow_ptr = srow + ((size_t)(task * 8 + jsp)) * BSZ;
#pragma unroll
  for (int mi = 0; mi < 2; mi++) {
#pragma unroll
    for (int r = 0; r < 4; r++) {
      float v = rs[mi][r];
      v += __shfl_xor(v, 1, 64);
      v += __shfl_xor(v, 2, 64);
      v += __shfl_xor(v, 4, 64);
      v += __shfl_xor(v, 8, 64);
      if (lm == 0) srow_ptr[rowg0 + mi * 16 + quad * 4 + r] = v;
    }
  }

  // ---- col-sum flush: one barrier, cross-wave LDS reduce, exclusive ----
  if (col_en) {
    __syncthreads();
    float* scol_ptr = scol + ((size_t)((task - 3) * 32 + ib)) * BSZ + jsp * 512;
    for (int c = tid; c < 512; c += 256)
      scol_ptr[c] = csLDS[c] + csLDS[512 + c] + csLDS[1024 + c] + csLDS[1536 + c];
  }
}

// ---------------------------------------------------------------------------
// Kernel 3: final loss reduction.  16 blocks x 256 threads, one row each.
// ---------------------------------------------------------------------------
__global__ __launch_bounds__(256) void reduce_kernel(
    const float* __restrict__ srow, const float* __restrict__ scol,
    const float* __restrict__ diag, float* __restrict__ out) {
  int tid = threadIdx.x;
  int i   = blockIdx.x * 256 + tid;

  float s[5];
#pragma unroll
  for (int t = 0; t < 5; t++) {
    float a = 0.f;
#pragma unroll
    for (int js = 0; js < 8; js++) a += srow[(size_t)(t * 8 + js) * BSZ + i];
    s[t] = a;
  }
  float s_zx = 0.f, s_zy = 0.f;
#pragma unroll 8
  for (int ib = 0; ib < 32; ib++) {
    s_zx += scol[(size_t)ib * BSZ + i];
    s_zy += scol[(size_t)(32 + ib) * BSZ + i];
  }
  float d_xx = diag[0 * BSZ + i], d_yy = diag[1 * BSZ + i];
  float d_xy = diag[2 * BSZ + i], d_ax = diag[3 * BSZ + i];
  float d_ay = diag[4 * BSZ + i];

  float denom = (s[2] - d_xy) + (s[0] - d_xx) + (s[1] - d_yy);
  float tloc = -2.0f * __logf(d_xy / denom);
  tloc -= __logf(d_ax / (s[3] - d_ax));
  tloc -= __logf(d_ay / (s[4] - d_ay));
  tloc -= __logf(d_ax / (s_zx - d_ax));   // d_zx == d_ax
  tloc -= __logf(d_ay / (s_zy - d_ay));   // d_zy == d_ay

  __shared__ float red[256];
  red[tid] = tloc;
  __syncthreads();
  for (int st = 128; st > 0; st >>= 1) {
    if (tid < st) red[tid] += red[tid + st];
    __syncthreads();
  }
  if (tid == 0) atomicAdd(out, red[0] / (float)BSZ);
}

// ---------------------------------------------------------------------------
extern "C" void kernel_launch(void* const* d_in, const int* in_sizes, int n_in,
                              void* d_out, int out_size, void* d_ws, size_t ws_size,
                              hipStream_t stream) {
  const float* x = (const float*)d_in[0];
  int rows = in_sizes[0] / D;   // 12288

  char*  ws       = (char*)d_ws;
  short* xnf      = (short*)ws;                        // 12288*128 bf16: 3 MiB
  size_t xn_bytes = (size_t)rows * D * sizeof(short);
  float* srow     = (float*)(ws + xn_bytes);           // [5][8][4096]: 640 KiB
  float* scol     = srow + 5 * 8 * BSZ;                // [2][32][4096]: 1 MiB
  float* diag     = scol + 2 * 32 * BSZ;               // [5][4096]: 80 KiB

  normalize_kernel<<<rows / 4, 256, 0, stream>>>(
      x, (__hip_bfloat162*)xnf, (float*)d_out, rows);
  expsim_kernel<<<GRID_EXPSIM, 256, 0, stream>>>(
      (const short8*)xnf, srow, scol, diag);
  reduce_kernel<<<16, 256, 0, stream>>>(srow, scol, diag, (float*)d_out);
}

// Round 7
// 99.285 us; speedup vs baseline: 1.1729x; 1.0137x over previous
//
#include <hip/hip_runtime.h>
#include <hip/hip_bf16.h>

// ---------------------------------------------------------------------------
// LossNet: x (12288,128) fp32 -> scalar loss.  bsz=4096.
// 5 matrices (zx/zy folded into colsums of xz/yz):
//   task 0 xx, 1 yy, 2 xy, 3 xz (+colsum->s_zx), 4 yz (+colsum->s_zy)
// Fragment-native layout (R6): every MFMA A/B fragment is ONE coalesced
// global_load_dwordx4; no LDS staging, no per-tile barriers.
// R7: rotating register prefetch of B fragments one tile ahead — R6 was
// latency-stall-bound (MFMA 18%, VALU 27%, occ 15%; L2 ~250cyc exposed).
// exp = __builtin_amdgcn_exp2f on prescaled inputs (1 inst).
// All reductions exclusive non-atomic stores (R3: atomics serialized).
// Timed-window floor note: harness poisons 268MB d_ws @6.3TB/s = 42.6us
// fixed — only expsim is a real lever.
// ---------------------------------------------------------------------------

typedef __attribute__((ext_vector_type(8))) short short8;   // 8 x bf16
typedef __attribute__((ext_vector_type(4))) float floatx4;  // MFMA acc

#define D   128
#define BSZ 4096
#define GPM 256          // 16-row groups per matrix (4096/16)
// expsim grid: 5 tasks x 32 iblk(128 rows) x 8 jsp(512 cols)
#define GRID_EXPSIM (5 * 32 * 8)

// ---------------------------------------------------------------------------
// Kernel 1: row-normalize fp32 -> bf16 into fragment-native layout,
// prescaled by sqrt(10*log2(e)).  One wave per row.  Also zeroes out[0].
// ---------------------------------------------------------------------------
__global__ __launch_bounds__(256) void normalize_kernel(
    const float* __restrict__ x, __hip_bfloat162* __restrict__ xnf2,
    float* __restrict__ out, int rows) {
  int tid = threadIdx.x;
  if (blockIdx.x == 0 && tid == 0) out[0] = 0.0f;

  int row  = blockIdx.x * 4 + (tid >> 6);
  int lane = tid & 63;
  if (row >= rows) return;
  const float2* xr = (const float2*)(x + (size_t)row * D);
  float2 v = xr[lane];
  float s = v.x * v.x + v.y * v.y;
#pragma unroll
  for (int off = 1; off < 64; off <<= 1) s += __shfl_xor(s, off, 64);
  // sqrt(10 / ln 2): dot(a,b) = 10*log2(e)*cos -> e^(10 cos) = exp2(dot)
  float scale = 3.7982825470322528f / fmaxf(sqrtf(s), 1e-12f);
  __hip_bfloat162 h;
  h.x = __float2bfloat16(v.x * scale);
  h.y = __float2bfloat16(v.y * scale);
  // fragment-native scatter: k0 = lane*2
  // short idx = g*2048 + kk*512 + (quad*16 + (row&15))*8 + j   (as bf162: /2)
  int g    = row >> 4;
  int kk   = lane >> 4;            // k0>>5
  int quad = (lane >> 2) & 3;      // (k0>>3)&3
  int jj   = lane & 3;             // (k0&7)/2
  xnf2[g * 1024 + kk * 256 + (quad * 16 + (row & 15)) * 4 + jj] = h;
}

// ---------------------------------------------------------------------------
// Epilogue: exp2 (1 inst), rowsum partials (regs), optional colsum partials,
// optional diag store.  C/D layout: col=lm, row=quad*4+reg  [m89-verified]
// ---------------------------------------------------------------------------
template <bool COL, bool DIAG>
__device__ __forceinline__ void epilogue(
    const floatx4 (&acc)[2][4], float (&rs)[2][4], float (&cs)[4],
    int rowg0, int colg0, int quad, int lm, float* __restrict__ diag_ptr) {
#pragma unroll
  for (int mi = 0; mi < 2; mi++) {
#pragma unroll
    for (int r = 0; r < 4; r++) {
      int rowg = rowg0 + mi * 16 + quad * 4 + r;
      float part = 0.f;
#pragma unroll
      for (int ni = 0; ni < 4; ni++) {
        float e = __builtin_amdgcn_exp2f(acc[mi][ni][r]);  // v_exp_f32
        part += e;
        if (COL) cs[ni] += e;
        if (DIAG) {
          if (colg0 + ni * 16 + lm == rowg) diag_ptr[rowg] = e;
        }
      }
      rs[mi][r] += part;
    }
  }
}

// ---------------------------------------------------------------------------
// Kernel 2: exp-sim, barrier-free K-loop with rotating B-register prefetch.
// block = (task, ib, jsp); wave w: rows ib*128+w*32..+32, cols jsp*512..+512.
// NOTE: plain __launch_bounds__(256) — min-waves cap spills (R2).
// ---------------------------------------------------------------------------
__global__ __launch_bounds__(256) void expsim_kernel(
    const short8* __restrict__ xnf8,
    float* __restrict__ srow,   // [5][8][4096] exclusive
    float* __restrict__ scol,   // [2][32][4096] exclusive
    float* __restrict__ diag) { // [5][4096] exclusive
  __shared__ float csLDS[4 * 512];   // colsum accum, tasks 3-4 only

  int tid = threadIdx.x;
  int bx  = blockIdx.x;
  int task = bx >> 8;          // 256 blocks per task
  int rem  = bx & 255;
  int ib   = rem >> 3;         // 32 row-blocks of 128
  int jsp  = rem & 7;          // 8 col-groups of 512

  const int aoff_t[5] = {0, 1, 0, 0, 1};
  const int boff_t[5] = {0, 1, 1, 2, 2};
  bool col_en = (task >= 3);

  int w    = tid >> 6;
  int lane = tid & 63;
  int quad = lane >> 4;
  int lm   = lane & 15;
  int rowg0 = ib * 128 + w * 32;

  // diagonal-owning tile: block-uniform jsp match; wave-local tile index
  bool dgblk = (jsp == (ib >> 2));
  int  tdiag = ((ib & 3) * 2) + (w >> 1);

  float* diag_ptr = diag + task * BSZ;

  // ---- A fragments (one coalesced b128 each), resident whole wave ----
  int gA = aoff_t[task] * GPM + ib * 8 + w * 2;
  short8 afrag[2][4];
#pragma unroll
  for (int mi = 0; mi < 2; mi++)
#pragma unroll
    for (int kk = 0; kk < 4; kk++)
      afrag[mi][kk] = xnf8[(size_t)(gA + mi) * 256 + kk * 64 + lane];

  float rs[2][4];
#pragma unroll
  for (int mi = 0; mi < 2; mi++)
#pragma unroll
    for (int r = 0; r < 4; r++) rs[mi][r] = 0.0f;

  const floatx4 z4 = {0.f, 0.f, 0.f, 0.f};
  // B fragment address helper: tile t, k-slab kk, col-subtile ni
  const short8* bbase = xnf8 + (size_t)(boff_t[task] * GPM + jsp * 32) * 256 + lane;

  // ---- rotating register prefetch: bf[kk*4+ni] holds tile t's fragments;
  // after kk's MFMAs consume them, the same regs are refilled for t+1.
  // Load->use distance: remaining MFMAs + full epilogue (~450 cyc) >> L2 lat.
  short8 bf[16];
#pragma unroll
  for (int i = 0; i < 16; i++)
    bf[i] = bbase[(size_t)(i & 3) * 256 + (i >> 2) * 64];

#pragma unroll 1
  for (int t = 0; t < 8; t++) {
    int colg0 = (jsp * 8 + t) * 64;
    floatx4 acc[2][4];
#pragma unroll
    for (int kk = 0; kk < 4; kk++) {
#pragma unroll
      for (int mi = 0; mi < 2; mi++)
#pragma unroll
        for (int ni = 0; ni < 4; ni++)
          acc[mi][ni] = __builtin_amdgcn_mfma_f32_16x16x32_bf16(
              afrag[mi][kk], bf[kk * 4 + ni], (kk == 0) ? z4 : acc[mi][ni],
              0, 0, 0);
      if (t < 7) {
        // refill this kk-slab for tile t+1 (WAR on bf is free: MFMA already
        // read operands at issue; loads retire behind epilogue's slack)
#pragma unroll
        for (int ni = 0; ni < 4; ni++)
          bf[kk * 4 + ni] = bbase[(size_t)((t + 1) * 4 + ni) * 256 + kk * 64];
      }
    }

    float cs[4] = {0.f, 0.f, 0.f, 0.f};
    bool dg = dgblk && (t == tdiag);   // wave-uniform
    if (col_en) {
      if (dg) epilogue<true, true>(acc, rs, cs, rowg0, colg0, quad, lm, diag_ptr);
      else    epilogue<true, false>(acc, rs, cs, rowg0, colg0, quad, lm, diag_ptr);
      // reduce across quads (rows within wave); each slot written once
#pragma unroll
      for (int ni = 0; ni < 4; ni++) {
        float v = cs[ni];
        v += __shfl_xor(v, 16, 64);
        v += __shfl_xor(v, 32, 64);
        if (quad == 0) csLDS[w * 512 + t * 64 + ni * 16 + lm] = v;
      }
    } else {
      if (dg) epilogue<false, true>(acc, rs, cs, rowg0, colg0, quad, lm, diag_ptr);
      else    epilogue<false, false>(acc, rs, cs, rowg0, colg0, quad, lm, diag_ptr);
    }
  }

  // ---- row-sum flush: reduce over lm within quad, exclusive store ----
  float* srow_ptr = srow + ((size_t)(task * 8 + jsp)) * BSZ;
#pragma unroll
  for (int mi = 0; mi < 2; mi++) {
#pragma unroll
    for (int r = 0; r < 4; r++) {
      float v = rs[mi][r];
      v += __shfl_xor(v, 1, 64);
      v += __shfl_xor(v, 2, 64);
      v += __shfl_xor(v, 4, 64);
      v += __shfl_xor(v, 8, 64);
      if (lm == 0) srow_ptr[rowg0 + mi * 16 + quad * 4 + r] = v;
    }
  }

  // ---- col-sum flush: one barrier, cross-wave LDS reduce, exclusive ----
  if (col_en) {
    __syncthreads();
    float* scol_ptr = scol + ((size_t)((task - 3) * 32 + ib)) * BSZ + jsp * 512;
    for (int c = tid; c < 512; c += 256)
      scol_ptr[c] = csLDS[c] + csLDS[512 + c] + csLDS[1024 + c] + csLDS[1536 + c];
  }
}

// ---------------------------------------------------------------------------
// Kernel 3: final loss reduction.  16 blocks x 256 threads, one row each.
// ---------------------------------------------------------------------------
__global__ __launch_bounds__(256) void reduce_kernel(
    const float* __restrict__ srow, const float* __restrict__ scol,
    const float* __restrict__ diag, float* __restrict__ out) {
  int tid = threadIdx.x;
  int i   = blockIdx.x * 256 + tid;

  float s[5];
#pragma unroll
  for (int t = 0; t < 5; t++) {
    float a = 0.f;
#pragma unroll
    for (int js = 0; js < 8; js++) a += srow[(size_t)(t * 8 + js) * BSZ + i];
    s[t] = a;
  }
  float s_zx = 0.f, s_zy = 0.f;
#pragma unroll 8
  for (int ib = 0; ib < 32; ib++) {
    s_zx += scol[(size_t)ib * BSZ + i];
    s_zy += scol[(size_t)(32 + ib) * BSZ + i];
  }
  float d_xx = diag[0 * BSZ + i], d_yy = diag[1 * BSZ + i];
  float d_xy = diag[2 * BSZ + i], d_ax = diag[3 * BSZ + i];
  float d_ay = diag[4 * BSZ + i];

  float denom = (s[2] - d_xy) + (s[0] - d_xx) + (s[1] - d_yy);
  float tloc = -2.0f * __logf(d_xy / denom);
  tloc -= __logf(d_ax / (s[3] - d_ax));
  tloc -= __logf(d_ay / (s[4] - d_ay));
  tloc -= __logf(d_ax / (s_zx - d_ax));   // d_zx == d_ax
  tloc -= __logf(d_ay / (s_zy - d_ay));   // d_zy == d_ay

  __shared__ float red[256];
  red[tid] = tloc;
  __syncthreads();
  for (int st = 128; st > 0; st >>= 1) {
    if (tid < st) red[tid] += red[tid + st];
    __syncthreads();
  }
  if (tid == 0) atomicAdd(out, red[0] / (float)BSZ);
}

// ---------------------------------------------------------------------------
extern "C" void kernel_launch(void* const* d_in, const int* in_sizes, int n_in,
                              void* d_out, int out_size, void* d_ws, size_t ws_size,
                              hipStream_t stream) {
  const float* x = (const float*)d_in[0];
  int rows = in_sizes[0] / D;   // 12288

  char*  ws       = (char*)d_ws;
  short* xnf      = (short*)ws;                        // 12288*128 bf16: 3 MiB
  size_t xn_bytes = (size_t)rows * D * sizeof(short);
  float* srow     = (float*)(ws + xn_bytes);           // [5][8][4096]: 640 KiB
  float* scol     = srow + 5 * 8 * BSZ;                // [2][32][4096]: 1 MiB
  float* diag     = scol + 2 * 32 * BSZ;               // [5][4096]: 80 KiB

  normalize_kernel<<<rows / 4, 256, 0, stream>>>(
      x, (__hip_bfloat162*)xnf, (float*)d_out, rows);
  expsim_kernel<<<GRID_EXPSIM, 256, 0, stream>>>(
      (const short8*)xnf, srow, scol, diag);
  reduce_kernel<<<16, 256, 0, stream>>>(srow, scol, diag, (float*)d_out);
}

// Round 8
// 97.212 us; speedup vs baseline: 1.1979x; 1.0213x over previous
//
#include <hip/hip_runtime.h>
#include <hip/hip_bf16.h>

// ---------------------------------------------------------------------------
// LossNet: x (12288,128) fp32 -> scalar loss.  bsz=4096.
// 5 matrices (zx/zy folded into colsums of xz/yz):
//   task 0 xx, 1 yy, 2 xy, 3 xz (+colsum->s_zx), 4 yz (+colsum->s_zy)
// Fragment-native layout (R6): every MFMA A/B fragment is ONE coalesced
// global_load_dwordx4; no LDS staging, no per-tile barriers.
// R8: 256x256 blocks, wave = 64 rows x 4 col-tiles.  R7 post-mortem: all 4
// waves loaded IDENTICAL B fragments (4x redundancy, ~700MB L1 traffic,
// issue/BW-bound — register prefetch was neutral).  This shape cuts VMEM
// traffic 1.7x and doubles MFMAs per B-load (16->32 per 16KB tile... 64 per
// wave-tile), making exp-VALU the per-tile critical pipe.
// exp = __builtin_amdgcn_exp2f on prescaled inputs (1 inst).
// All reductions exclusive non-atomic stores (R3: atomics serialized).
// Timed-window floor: harness poison fill of d_ws = ~42us fixed.
// ---------------------------------------------------------------------------

typedef __attribute__((ext_vector_type(8))) short short8;   // 8 x bf16
typedef __attribute__((ext_vector_type(4))) float floatx4;  // MFMA acc

#define D   128
#define BSZ 4096
#define GPM 256          // 16-row groups per matrix (4096/16)
// expsim grid: 5 tasks x 16 rb(256 rows) x 16 cb(256 cols)
#define GRID_EXPSIM (5 * 16 * 16)

// ---------------------------------------------------------------------------
// Kernel 1: row-normalize fp32 -> bf16 into fragment-native layout,
// prescaled by sqrt(10*log2(e)).  One wave per row.  Also zeroes out[0].
// ---------------------------------------------------------------------------
__global__ __launch_bounds__(256) void normalize_kernel(
    const float* __restrict__ x, __hip_bfloat162* __restrict__ xnf2,
    float* __restrict__ out, int rows) {
  int tid = threadIdx.x;
  if (blockIdx.x == 0 && tid == 0) out[0] = 0.0f;

  int row  = blockIdx.x * 4 + (tid >> 6);
  int lane = tid & 63;
  if (row >= rows) return;
  const float2* xr = (const float2*)(x + (size_t)row * D);
  float2 v = xr[lane];
  float s = v.x * v.x + v.y * v.y;
#pragma unroll
  for (int off = 1; off < 64; off <<= 1) s += __shfl_xor(s, off, 64);
  // sqrt(10 / ln 2): dot(a,b) = 10*log2(e)*cos -> e^(10 cos) = exp2(dot)
  float scale = 3.7982825470322528f / fmaxf(sqrtf(s), 1e-12f);
  __hip_bfloat162 h;
  h.x = __float2bfloat16(v.x * scale);
  h.y = __float2bfloat16(v.y * scale);
  // fragment-native scatter: k0 = lane*2
  // short idx = g*2048 + kk*512 + (quad*16 + (row&15))*8 + j   (as bf162: /2)
  int g    = row >> 4;
  int kk   = lane >> 4;            // k0>>5
  int quad = (lane >> 2) & 3;      // (k0>>3)&3
  int jj   = lane & 3;             // (k0&7)/2
  xnf2[g * 1024 + kk * 256 + (quad * 16 + (row & 15)) * 4 + jj] = h;
}

// ---------------------------------------------------------------------------
// Epilogue: exp2 (1 inst), rowsum partials (regs), optional colsum partials,
// optional diag store.  C/D layout: col=lm, row=quad*4+reg  [m89-verified]
// ---------------------------------------------------------------------------
template <bool COL, bool DIAG>
__device__ __forceinline__ void epilogue(
    const floatx4 (&acc)[4][4], float (&rs)[4][4], float (&cs)[4],
    int rowg0, int colg0, int quad, int lm, float* __restrict__ diag_ptr) {
#pragma unroll
  for (int mi = 0; mi < 4; mi++) {
#pragma unroll
    for (int r = 0; r < 4; r++) {
      int rowg = rowg0 + mi * 16 + quad * 4 + r;
      float part = 0.f;
#pragma unroll
      for (int ni = 0; ni < 4; ni++) {
        float e = __builtin_amdgcn_exp2f(acc[mi][ni][r]);  // v_exp_f32
        part += e;
        if (COL) cs[ni] += e;
        if (DIAG) {
          if (colg0 + ni * 16 + lm == rowg) diag_ptr[rowg] = e;
        }
      }
      rs[mi][r] += part;
    }
  }
}

// ---------------------------------------------------------------------------
// Kernel 2: exp-sim, barrier-free K-loop.  block = (task, rb, cb) covering
// 256x256; wave w owns rows rb*256+w*64..+64 across all 4 col-tiles.
// NOTE: plain __launch_bounds__(256) — min-waves cap spills (R2).
// ---------------------------------------------------------------------------
__global__ __launch_bounds__(256) void expsim_kernel(
    const short8* __restrict__ xnf8,
    float* __restrict__ srow,   // [5][16][4096] exclusive
    float* __restrict__ scol,   // [2][16][4096] exclusive
    float* __restrict__ diag) { // [5][4096] exclusive
  __shared__ float csLDS[4 * 256];   // colsum accum, tasks 3-4 only

  int tid = threadIdx.x;
  int bx  = blockIdx.x;
  int task = bx >> 8;          // 256 blocks per task
  int rem  = bx & 255;
  int rb   = rem >> 4;         // 16 row-blocks of 256
  int cb   = rem & 15;         // 16 col-blocks of 256

  const int aoff_t[5] = {0, 1, 0, 0, 1};
  const int boff_t[5] = {0, 1, 1, 2, 2};
  bool col_en = (task >= 3);

  int w    = tid >> 6;
  int lane = tid & 63;
  int quad = lane >> 4;
  int lm   = lane & 15;
  int rowg0 = rb * 256 + w * 64;

  // wave w's diagonal tile is t==w when rb==cb (256x256 diagonal block)
  bool dgblk = (rb == cb);

  float* diag_ptr = diag + task * BSZ;

  // ---- A fragments (one coalesced b128 each), resident whole wave ----
  int gA = aoff_t[task] * GPM + rb * 16 + w * 4;
  short8 afrag[4][4];
#pragma unroll
  for (int mi = 0; mi < 4; mi++)
#pragma unroll
    for (int kk = 0; kk < 4; kk++)
      afrag[mi][kk] = xnf8[(size_t)(gA + mi) * 256 + kk * 64 + lane];

  float rs[4][4];
#pragma unroll
  for (int mi = 0; mi < 4; mi++)
#pragma unroll
    for (int r = 0; r < 4; r++) rs[mi][r] = 0.0f;

  const floatx4 z4 = {0.f, 0.f, 0.f, 0.f};
  const short8* bbase = xnf8 + (size_t)(boff_t[task] * GPM + cb * 16) * 256 + lane;

  // ---- 4 col-tiles, no barriers ----
#pragma unroll 1
  for (int t = 0; t < 4; t++) {
    int colg0 = cb * 256 + t * 64;

    short8 bf[16];   // bf[kk*4+ni]
#pragma unroll
    for (int i = 0; i < 16; i++)
      bf[i] = bbase[(size_t)(t * 4 + (i & 3)) * 256 + (i >> 2) * 64];

    floatx4 acc[4][4];
#pragma unroll
    for (int kk = 0; kk < 4; kk++)
#pragma unroll
      for (int mi = 0; mi < 4; mi++)
#pragma unroll
        for (int ni = 0; ni < 4; ni++)
          acc[mi][ni] = __builtin_amdgcn_mfma_f32_16x16x32_bf16(
              afrag[mi][kk], bf[kk * 4 + ni], (kk == 0) ? z4 : acc[mi][ni],
              0, 0, 0);

    float cs[4] = {0.f, 0.f, 0.f, 0.f};
    bool dg = dgblk && (t == w);   // wave-uniform
    if (col_en) {
      if (dg) epilogue<true, true>(acc, rs, cs, rowg0, colg0, quad, lm, diag_ptr);
      else    epilogue<true, false>(acc, rs, cs, rowg0, colg0, quad, lm, diag_ptr);
      // reduce across quads (64 rows of this wave); each slot written once
#pragma unroll
      for (int ni = 0; ni < 4; ni++) {
        float v = cs[ni];
        v += __shfl_xor(v, 16, 64);
        v += __shfl_xor(v, 32, 64);
        if (quad == 0) csLDS[w * 256 + t * 64 + ni * 16 + lm] = v;
      }
    } else {
      if (dg) epilogue<false, true>(acc, rs, cs, rowg0, colg0, quad, lm, diag_ptr);
      else    epilogue<false, false>(acc, rs, cs, rowg0, colg0, quad, lm, diag_ptr);
    }
  }

  // ---- row-sum flush: reduce over lm within quad, exclusive store ----
  float* srow_ptr = srow + ((size_t)(task * 16 + cb)) * BSZ;
#pragma unroll
  for (int mi = 0; mi < 4; mi++) {
#pragma unroll
    for (int r = 0; r < 4; r++) {
      float v = rs[mi][r];
      v += __shfl_xor(v, 1, 64);
      v += __shfl_xor(v, 2, 64);
      v += __shfl_xor(v, 4, 64);
      v += __shfl_xor(v, 8, 64);
      if (lm == 0) srow_ptr[rowg0 + mi * 16 + quad * 4 + r] = v;
    }
  }

  // ---- col-sum flush: one barrier, cross-wave LDS reduce, exclusive ----
  if (col_en) {
    __syncthreads();
    float* scol_ptr = scol + ((size_t)((task - 3) * 16 + rb)) * BSZ + cb * 256;
    scol_ptr[tid] = csLDS[tid] + csLDS[256 + tid] + csLDS[512 + tid] + csLDS[768 + tid];
  }
}

// ---------------------------------------------------------------------------
// Kernel 3: final loss reduction.  16 blocks x 256 threads, one row each.
// ---------------------------------------------------------------------------
__global__ __launch_bounds__(256) void reduce_kernel(
    const float* __restrict__ srow, const float* __restrict__ scol,
    const float* __restrict__ diag, float* __restrict__ out) {
  int tid = threadIdx.x;
  int i   = blockIdx.x * 256 + tid;

  float s[5];
#pragma unroll
  for (int t = 0; t < 5; t++) {
    float a = 0.f;
#pragma unroll
    for (int js = 0; js < 16; js++) a += srow[(size_t)(t * 16 + js) * BSZ + i];
    s[t] = a;
  }
  float s_zx = 0.f, s_zy = 0.f;
#pragma unroll 8
  for (int ib = 0; ib < 16; ib++) {
    s_zx += scol[(size_t)ib * BSZ + i];
    s_zy += scol[(size_t)(16 + ib) * BSZ + i];
  }
  float d_xx = diag[0 * BSZ + i], d_yy = diag[1 * BSZ + i];
  float d_xy = diag[2 * BSZ + i], d_ax = diag[3 * BSZ + i];
  float d_ay = diag[4 * BSZ + i];

  float denom = (s[2] - d_xy) + (s[0] - d_xx) + (s[1] - d_yy);
  float tloc = -2.0f * __logf(d_xy / denom);
  tloc -= __logf(d_ax / (s[3] - d_ax));
  tloc -= __logf(d_ay / (s[4] - d_ay));
  tloc -= __logf(d_ax / (s_zx - d_ax));   // d_zx == d_ax
  tloc -= __logf(d_ay / (s_zy - d_ay));   // d_zy == d_ay

  __shared__ float red[256];
  red[tid] = tloc;
  __syncthreads();
  for (int st = 128; st > 0; st >>= 1) {
    if (tid < st) red[tid] += red[tid + st];
    __syncthreads();
  }
  if (tid == 0) atomicAdd(out, red[0] / (float)BSZ);
}

// ---------------------------------------------------------------------------
extern "C" void kernel_launch(void* const* d_in, const int* in_sizes, int n_in,
                              void* d_out, int out_size, void* d_ws, size_t ws_size,
                              hipStream_t stream) {
  const float* x = (const float*)d_in[0];
  int rows = in_sizes[0] / D;   // 12288

  char*  ws       = (char*)d_ws;
  short* xnf      = (short*)ws;                        // 12288*128 bf16: 3 MiB
  size_t xn_bytes = (size_t)rows * D * sizeof(short);
  float* srow     = (float*)(ws + xn_bytes);           // [5][16][4096]: 1.25 MiB
  float* scol     = srow + 5 * 16 * BSZ;               // [2][16][4096]: 512 KiB
  float* diag     = scol + 2 * 16 * BSZ;               // [5][4096]: 80 KiB

  normalize_kernel<<<rows / 4, 256, 0, stream>>>(
      x, (__hip_bfloat162*)xnf, (float*)d_out, rows);
  expsim_kernel<<<GRID_EXPSIM, 256, 0, stream>>>(
      (const short8*)xnf, srow, scol, diag);
  reduce_kernel<<<16, 256, 0, stream>>>(srow, scol, diag, (float*)d_out);
}